// Round 4
// baseline (146.492 us; speedup 1.0000x reference)
//
#include <hip/hip_runtime.h>
#include <hip/hip_bf16.h>

#define S_LEN 4096
#define D_DIM 64
#define NBATCH 4

typedef unsigned short u16;
typedef unsigned int u32;
typedef __attribute__((ext_vector_type(8))) __bf16 bf16x8;
typedef __attribute__((ext_vector_type(4))) float f32x4;
typedef __attribute__((ext_vector_type(16))) float f32x16;

__device__ __forceinline__ u16 f_to_bf16u(float f) {
    union { float f; u32 u; } x; x.f = f;
    u32 r = x.u + 0x7fffu + ((x.u >> 16) & 1u);   // RNE; inputs finite
    return (u16)(r >> 16);
}

// ---------------------------------------------------------------------------
// QKV projection. Q PRE-SCALED by 0.125*log2(e). V written transposed Vt[b][d][s].
// ---------------------------------------------------------------------------
__global__ __launch_bounds__(256, 2)
void proj_qkv_kernel(const float* __restrict__ q, const float* __restrict__ k,
                     const float* __restrict__ v,
                     const float* __restrict__ Wq, const float* __restrict__ bq,
                     const float* __restrict__ Wk, const float* __restrict__ bk,
                     const float* __restrict__ Wv, const float* __restrict__ bv,
                     u16* __restrict__ Qb, u16* __restrict__ Kb, u16* __restrict__ Vt)
{
    __shared__ __align__(16) u16 vt[64 * 72];

    const int p = blockIdx.y;
    const float* inp  = (p == 0) ? q  : (p == 1) ? k  : v;
    const float* W    = (p == 0) ? Wq : (p == 1) ? Wk : Wv;
    const float* bias = (p == 0) ? bq : (p == 1) ? bk : bv;
    const float scl   = (p == 0) ? 0.18033688011112042f : 1.0f;

    const int tid  = threadIdx.x;
    const int wid  = tid >> 6;
    const int lane = tid & 63;
    const int ln   = lane & 15;
    const int qd   = lane >> 4;
    const int row0 = blockIdx.x * 64;
    const int r0w  = row0 + wid * 16;

    bf16x8 afrag[2];
#pragma unroll
    for (int c = 0; c < 2; ++c) {
        const float* src = inp + (r0w + ln) * 64 + c * 32 + qd * 8;
        float4 f0 = *(const float4*)src;
        float4 f1 = *(const float4*)(src + 4);
        bf16x8 a;
        a[0] = (__bf16)f0.x; a[1] = (__bf16)f0.y; a[2] = (__bf16)f0.z; a[3] = (__bf16)f0.w;
        a[4] = (__bf16)f1.x; a[5] = (__bf16)f1.y; a[6] = (__bf16)f1.z; a[7] = (__bf16)f1.w;
        afrag[c] = a;
    }

    bf16x8 bfrag[4][2];
    float  bcol[4];
#pragma unroll
    for (int nb = 0; nb < 4; ++nb) {
        bcol[nb] = bias[nb * 16 + ln];
#pragma unroll
        for (int c = 0; c < 2; ++c) {
            const float* src = W + (nb * 16 + ln) * 64 + c * 32 + qd * 8;
            float4 f0 = *(const float4*)src;
            float4 f1 = *(const float4*)(src + 4);
            bf16x8 b;
            b[0] = (__bf16)f0.x; b[1] = (__bf16)f0.y; b[2] = (__bf16)f0.z; b[3] = (__bf16)f0.w;
            b[4] = (__bf16)f1.x; b[5] = (__bf16)f1.y; b[6] = (__bf16)f1.z; b[7] = (__bf16)f1.w;
            bfrag[nb][c] = b;
        }
    }

    f32x4 acc[4];
#pragma unroll
    for (int nb = 0; nb < 4; ++nb) acc[nb] = (f32x4){0.f, 0.f, 0.f, 0.f};
#pragma unroll
    for (int c = 0; c < 2; ++c)
#pragma unroll
        for (int nb = 0; nb < 4; ++nb)
            acc[nb] = __builtin_amdgcn_mfma_f32_16x16x32_bf16(afrag[c], bfrag[nb][c], acc[nb], 0, 0, 0);

    if (p < 2) {
        u16* dst = (p == 0) ? Qb : Kb;
#pragma unroll
        for (int nb = 0; nb < 4; ++nb)
#pragma unroll
            for (int r = 0; r < 4; ++r) {
                int row = r0w + qd * 4 + r;
                dst[row * 64 + nb * 16 + ln] = f_to_bf16u((acc[nb][r] + bcol[nb]) * scl);
            }
    } else {
#pragma unroll
        for (int nb = 0; nb < 4; ++nb)
#pragma unroll
            for (int r = 0; r < 4; ++r)
                vt[(wid * 16 + qd * 4 + r) * 72 + nb * 16 + ln] = f_to_bf16u(acc[nb][r] + bcol[nb]);
        __syncthreads();
        const int d  = tid >> 2;
        const int sc = tid & 3;
        const int b  = row0 >> 12;
        const int sb = row0 & 4095;
        __align__(16) u16 tmp[16];
#pragma unroll
        for (int i = 0; i < 16; ++i) tmp[i] = vt[(sc * 16 + i) * 72 + d];
        u16* dstp = Vt + (size_t)b * (64 * S_LEN) + d * S_LEN + sb + sc * 16;
        *(uint4*)(dstp)     = *(const uint4*)(tmp);
        *(uint4*)(dstp + 8) = *(const uint4*)(tmp + 8);
    }
}

// ---------------------------------------------------------------------------
// Flash v4: 128x128 block tile, wave = 64q x 64k (2x reuse per ds_read),
// 72-padded P buffer (conflict-free), sequential band-pair (p, 31-p) for
// exact balance (34 jt-tiles / 4 chunks = 8-9 iters per block), 1 block/CU.
// Dynamic LDS: kv 64 KB (double-buffered K 128x64 + V 64x128) + pbuf 36 KB.
// ---------------------------------------------------------------------------
__global__ __launch_bounds__(256, 1)
void flash_kernel(const u16* __restrict__ Qb, const u16* __restrict__ Kb,
                  const u16* __restrict__ Vt, u16* __restrict__ Op,
                  float* __restrict__ Lp)
{
    extern __shared__ __align__(16) u16 dynlds[];
    u16* kvbuf = dynlds;                 // [2][2][8192]
    u16* pbuf  = dynlds + 32768;         // [4][64*72]

    const int tid   = threadIdx.x;
    const int wid   = tid >> 6;
    const int lane  = tid & 63;
    const int l31   = lane & 31;
    const int lh    = lane >> 5;
    const int qhalf = wid & 1;
    const int khalf = wid >> 1;

    const int bid   = blockIdx.x;
    const int batch = bid & 3;            // XCD x -> single batch (x&3)
    const int c     = (bid >> 2) & 3;     // j-chunk
    const int p     = bid >> 4;           // band pair 0..15

    // staging: every thread stages 64 B of K and 64 B of V per tile
    const int  srow = tid >> 1;           // K row 0..127
    const int  sch0 = (tid & 1) * 4;
    const int  vrow = tid >> 2;           // V row (d) 0..63
    const int  vch0 = (tid & 3) * 4;
    const u16* kgp  = Kb + ((size_t)batch * S_LEN + srow) * 64;
    const u16* vgp  = Vt + (size_t)batch * (64 * S_LEN) + (size_t)vrow * S_LEN;

    u16* pw = pbuf + wid * (64 * 72);
    int cur = 0;

    for (int ph = 0; ph < 2; ++ph) {
        const int band = ph ? (31 - p) : p;
        const int jt0  = band + ((c - band) & 3);

        // Q B-frags: B[k=d][n=qrow], lane n = l31
        bf16x8 qf[2][4];
        {
            const u16* qb = Qb + ((size_t)batch * S_LEN + band * 128 + qhalf * 64 + l31) * 64;
#pragma unroll
            for (int ni = 0; ni < 2; ++ni)
#pragma unroll
                for (int c2 = 0; c2 < 4; ++c2)
                    qf[ni][c2] = *(const bf16x8*)(qb + ni * (32 * 64) + c2 * 16 + lh * 8);
        }

        f32x16 o00, o01, o10, o11;
#pragma unroll
        for (int r = 0; r < 16; ++r) { o00[r] = 0.f; o01[r] = 0.f; o10[r] = 0.f; o11[r] = 0.f; }
        float ls0 = 0.f, ls1 = 0.f;

        if (jt0 < 32) {
            {   // stage first tile of this phase into kv[cur]
                const int j0 = jt0 * 128;
                const uint4* gk = (const uint4*)(kgp + (size_t)j0 * 64);
                u16* kb = kvbuf + cur * 16384 + srow * 64;
#pragma unroll
                for (int i = 0; i < 4; ++i)
                    *(uint4*)(kb + ((sch0 + i) ^ (srow & 7)) * 8) = gk[sch0 + i];
                const uint4* gv = (const uint4*)(vgp + j0);
                u16* vb = kvbuf + cur * 16384 + 8192 + vrow * 128;
#pragma unroll
                for (int i = 0; i < 4; ++i) {
                    const int chv = vch0 + i;
                    *(uint4*)(vb + ((chv & 8) | ((chv ^ vrow) & 7)) * 8) = gv[chv];
                }
            }

            for (int jt = jt0; jt < 32; jt += 4) {
                __syncthreads();
                const bool more = (jt + 4) < 32;
                uint4 kpf[4], vpf[4];
                if (more) {
                    const int jn = (jt + 4) * 128;
                    const uint4* gk = (const uint4*)(kgp + (size_t)jn * 64);
#pragma unroll
                    for (int i = 0; i < 4; ++i) kpf[i] = gk[sch0 + i];
                    const uint4* gv = (const uint4*)(vgp + jn);
#pragma unroll
                    for (int i = 0; i < 4; ++i) vpf[i] = gv[vch0 + i];
                }
                const u16* kb = kvbuf + cur * 16384;
                const u16* vb = kvbuf + cur * 16384 + 8192;
                const bool dm = (jt == band);

                // ---- S^T = K*Q^T per kcol-mtile; softmax; P -> padded LDS
#pragma unroll
                for (int mi = 0; mi < 2; ++mi) {
                    f32x16 s0, s1;
#pragma unroll
                    for (int r = 0; r < 16; ++r) { s0[r] = 0.f; s1[r] = 0.f; }
                    const int rK = khalf * 64 + mi * 32 + l31;
#pragma unroll
                    for (int c2 = 0; c2 < 4; ++c2) {
                        bf16x8 a = *(const bf16x8*)(kb + rK * 64 + (((2 * c2 + lh) ^ (rK & 7)) * 8));
                        s0 = __builtin_amdgcn_mfma_f32_32x32x16_bf16(a, qf[0][c2], s0, 0, 0, 0);
                        s1 = __builtin_amdgcn_mfma_f32_32x32x16_bf16(a, qf[1][c2], s1, 0, 0, 0);
                    }
#pragma unroll
                    for (int ni = 0; ni < 2; ++ni) {
                        float lacc = 0.f;
#pragma unroll
                        for (int g = 0; g < 4; ++g) {
                            float p0, p1, p2, p3;
                            {
                                const f32x16& s = ni ? s1 : s0;
                                p0 = exp2f(s[g * 4 + 0]);
                                p1 = exp2f(s[g * 4 + 1]);
                                p2 = exp2f(s[g * 4 + 2]);
                                p3 = exp2f(s[g * 4 + 3]);
                            }
                            if (dm) {   // jt == band: band*128 cancels
                                const int kg = khalf * 64 + mi * 32 + 8 * g + 4 * lh;
                                const int qg = qhalf * 64 + ni * 32 + l31;
                                p0 = (kg + 0 < qg) ? 0.f : p0;
                                p1 = (kg + 1 < qg) ? 0.f : p1;
                                p2 = (kg + 2 < qg) ? 0.f : p2;
                                p3 = (kg + 3 < qg) ? 0.f : p3;
                            }
                            lacc += (p0 + p1) + (p2 + p3);
                            u32 w0 = (u32)f_to_bf16u(p0) | ((u32)f_to_bf16u(p1) << 16);
                            u32 w1 = (u32)f_to_bf16u(p2) | ((u32)f_to_bf16u(p3) << 16);
                            *(uint2*)(pw + (ni * 32 + l31) * 72 + mi * 32 + g * 8 + 4 * lh) = make_uint2(w0, w1);
                        }
                        if (ni) ls1 += lacc; else ls0 += lacc;
                    }
                }

                // ---- O += P*V : A = P (m=qrow), B = V (n=d)
#pragma unroll
                for (int c2 = 0; c2 < 4; ++c2) {
                    bf16x8 pa0 = *(const bf16x8*)(pw + l31 * 72 + c2 * 16 + lh * 8);
                    bf16x8 pa1 = *(const bf16x8*)(pw + (32 + l31) * 72 + c2 * 16 + lh * 8);
                    const int chv = khalf * 8 + c2 * 2 + lh;
                    const int r0 = l31, r1 = 32 + l31;
                    bf16x8 v0 = *(const bf16x8*)(vb + r0 * 128 + (((chv & 8) | ((chv ^ (r0 & 7)) & 7)) * 8));
                    bf16x8 v1 = *(const bf16x8*)(vb + r1 * 128 + (((chv & 8) | ((chv ^ (r1 & 7)) & 7)) * 8));
                    o00 = __builtin_amdgcn_mfma_f32_32x32x16_bf16(pa0, v0, o00, 0, 0, 0);
                    o01 = __builtin_amdgcn_mfma_f32_32x32x16_bf16(pa0, v1, o01, 0, 0, 0);
                    o10 = __builtin_amdgcn_mfma_f32_32x32x16_bf16(pa1, v0, o10, 0, 0, 0);
                    o11 = __builtin_amdgcn_mfma_f32_32x32x16_bf16(pa1, v1, o11, 0, 0, 0);
                }

                if (more) {
                    u16* kb2 = kvbuf + (cur ^ 1) * 16384 + srow * 64;
#pragma unroll
                    for (int i = 0; i < 4; ++i)
                        *(uint4*)(kb2 + ((sch0 + i) ^ (srow & 7)) * 8) = kpf[i];
                    u16* vb2 = kvbuf + (cur ^ 1) * 16384 + 8192 + vrow * 128;
#pragma unroll
                    for (int i = 0; i < 4; ++i) {
                        const int chv = vch0 + i;
                        *(uint4*)(vb2 + ((chv & 8) | ((chv ^ vrow) & 7)) * 8) = vpf[i];
                    }
                }
                cur ^= 1;
            }
        }

        // ---- epilogue: unnormalized partials for (band, c, khalf)
        const int slot = ((batch * 32 + band) * 4 + c) * 2 + khalf;
        u16* ob = Op + (size_t)slot * 8192;
#pragma unroll
        for (int r = 0; r < 16; ++r) {
            const int rowf = (r & 3) + 8 * (r >> 2) + 4 * lh;
            const int r0   = (qhalf * 64 + rowf) * 64;
            const int r1   = (qhalf * 64 + 32 + rowf) * 64;
            ob[r0 + l31]      = f_to_bf16u(o00[r]);
            ob[r0 + 32 + l31] = f_to_bf16u(o01[r]);
            ob[r1 + l31]      = f_to_bf16u(o10[r]);
            ob[r1 + 32 + l31] = f_to_bf16u(o11[r]);
        }
        ls0 += __shfl_xor(ls0, 32);
        ls1 += __shfl_xor(ls1, 32);
        if (lh == 0) {
            Lp[slot * 128 + qhalf * 64 + l31]      = ls0;
            Lp[slot * 128 + qhalf * 64 + 32 + l31] = ls1;
        }
    }
}

// ---------------------------------------------------------------------------
// Combine 8 partials/row (4 chunks x 2 kcol-halves, pure sums) + out proj.
// ---------------------------------------------------------------------------
__global__ __launch_bounds__(256, 2)
void combine_proj_kernel(const u16* __restrict__ Op, const float* __restrict__ Lp,
                         const float* __restrict__ Wp, const float* __restrict__ bp,
                         float* __restrict__ out)
{
    const int tid  = threadIdx.x;
    const int wid  = tid >> 6;
    const int lane = tid & 63;
    const int ln   = lane & 15;
    const int qd   = lane >> 4;
    const int g    = blockIdx.x * 64 + wid * 16;
    const int row  = g + ln;

    const int batch = row >> 12;
    const int sr    = row & 4095;
    const int band  = sr >> 7;
    const int rl    = sr & 127;
    const int sbase = ((batch * 32 + band) * 4) * 2;

    float acc0[8], acc1[8];
#pragma unroll
    for (int j = 0; j < 8; ++j) { acc0[j] = 0.f; acc1[j] = 0.f; }
    float l = 0.f;
#pragma unroll
    for (int s = 0; s < 8; ++s) {
        const int slot = sbase + s;
        const u16* op = Op + (size_t)slot * 8192 + rl * 64 + qd * 8;
        bf16x8 x0 = *(const bf16x8*)op;
        bf16x8 x1 = *(const bf16x8*)(op + 32);
#pragma unroll
        for (int j = 0; j < 8; ++j) { acc0[j] += (float)x0[j]; acc1[j] += (float)x1[j]; }
        l += Lp[slot * 128 + rl];
    }
    float inv = 1.0f / l;
    bf16x8 afrag[2];
#pragma unroll
    for (int j = 0; j < 8; ++j) { afrag[0][j] = (__bf16)(acc0[j] * inv); afrag[1][j] = (__bf16)(acc1[j] * inv); }

    bf16x8 bfrag[4][2];
    float  bcol[4];
#pragma unroll
    for (int nb = 0; nb < 4; ++nb) {
        bcol[nb] = bp[nb * 16 + ln];
#pragma unroll
        for (int cc = 0; cc < 2; ++cc) {
            const float* src = Wp + (nb * 16 + ln) * 64 + cc * 32 + qd * 8;
            float4 f0 = *(const float4*)src;
            float4 f1 = *(const float4*)(src + 4);
            bf16x8 b;
            b[0] = (__bf16)f0.x; b[1] = (__bf16)f0.y; b[2] = (__bf16)f0.z; b[3] = (__bf16)f0.w;
            b[4] = (__bf16)f1.x; b[5] = (__bf16)f1.y; b[6] = (__bf16)f1.z; b[7] = (__bf16)f1.w;
            bfrag[nb][cc] = b;
        }
    }

    f32x4 acc[4];
#pragma unroll
    for (int nb = 0; nb < 4; ++nb) acc[nb] = (f32x4){0.f, 0.f, 0.f, 0.f};
#pragma unroll
    for (int cc = 0; cc < 2; ++cc)
#pragma unroll
        for (int nb = 0; nb < 4; ++nb)
            acc[nb] = __builtin_amdgcn_mfma_f32_16x16x32_bf16(afrag[cc], bfrag[nb][cc], acc[nb], 0, 0, 0);

#pragma unroll
    for (int nb = 0; nb < 4; ++nb)
#pragma unroll
        for (int r = 0; r < 4; ++r) {
            int rowo = g + qd * 4 + r;
            out[(size_t)rowo * 64 + nb * 16 + ln] = acc[nb][r] + bcol[nb];
        }
}

extern "C" void kernel_launch(void* const* d_in, const int* in_sizes, int n_in,
                              void* d_out, int out_size, void* d_ws, size_t ws_size,
                              hipStream_t stream) {
    const float* q  = (const float*)d_in[0];
    const float* k  = (const float*)d_in[1];
    const float* v  = (const float*)d_in[2];
    const float* Wq = (const float*)d_in[3];
    const float* bq = (const float*)d_in[4];
    const float* Wk = (const float*)d_in[5];
    const float* bk = (const float*)d_in[6];
    const float* Wv = (const float*)d_in[7];
    const float* bv = (const float*)d_in[8];
    const float* Wp = (const float*)d_in[9];
    const float* bp = (const float*)d_in[10];
    float* out = (float*)d_out;

    const size_t NTOK = (size_t)NBATCH * S_LEN * D_DIM;   // 1,048,576
    u16* Qb = (u16*)d_ws;                                  // 2 MB
    u16* Kb = Qb + NTOK;                                   // 2 MB
    u16* Vt = Kb + NTOK;                                   // 2 MB
    u16* Op = Vt + NTOK;                                   // 1024 slots * 16 KB = 16 MB
    float* Lp = (float*)(Op + (size_t)1024 * 8192);        // 512 KB

    static bool attr_set = false;
    if (!attr_set) {
        hipFuncSetAttribute((const void*)flash_kernel,
                            hipFuncAttributeMaxDynamicSharedMemorySize, 102400);
        attr_set = true;
    }

    proj_qkv_kernel<<<dim3(256, 3), 256, 0, stream>>>(q, k, v, Wq, bq, Wk, bk, Wv, bv, Qb, Kb, Vt);
    flash_kernel<<<256, 256, 102400, stream>>>(Qb, Kb, Vt, Op, Lp);
    combine_proj_kernel<<<256, 256, 0, stream>>>(Op, Lp, Wp, bp, out);
}